// Round 11
// baseline (164.781 us; speedup 1.0000x reference)
//
#include <hip/hip_runtime.h>
#include <hip/hip_bf16.h>

#define B_ 8
#define N_ 512

typedef __attribute__((ext_vector_type(8))) __bf16 bf16x8;
typedef __attribute__((ext_vector_type(4))) float f32x4;
typedef __attribute__((ext_vector_type(4))) unsigned int u32x4;

// pack two fp32 into bf16x2 by truncation: 1 v_perm_b32
__device__ __forceinline__ unsigned pk_bf16(float hi, float lo) {
    return __builtin_amdgcn_perm(__builtin_bit_cast(unsigned, hi),
                                 __builtin_bit_cast(unsigned, lo), 0x07060302u);
}

// ---------------- stage 1: fused node-MLP | weight-prep | zero-out ----------
// [0,2048)     node MLP, 2 rows/block (16 waves/CU TLP)
// [2048,2816)  w0t transpose (coalesced reads)
// [2816,3072)  w1t transpose
// [3072,3104)  aw1p fragment pack
// [3104,3112)  zero d_out
// 3112         eb/ew epilogue constants
__global__ __launch_bounds__(128) void k_stage1(
    const float* __restrict__ coords,
    const float* __restrict__ fw0, const float* __restrict__ fb0,
    const float* __restrict__ fw1, const float* __restrict__ fb1,
    const float* __restrict__ aw1,
    const float* __restrict__ ab1, const float* __restrict__ aw2,
    const float* __restrict__ uw0, const float* __restrict__ uw1,
    __bf16* __restrict__ h_bf, __bf16* __restrict__ h_t,
    __bf16* __restrict__ w0t, __bf16* __restrict__ w1t,
    __bf16* __restrict__ aw1p, float* __restrict__ eb, float* __restrict__ ew,
    float* __restrict__ out, int out_size)
{
    const int blk = blockIdx.x;
    const int t = threadIdx.x;

    if (blk < 2048) {
        // ---- node MLP: rows row0, row0+1 (same batch) ----
        const int row0 = blk << 1;
        const int b = row0 >> 9;
        const int n0 = row0 & 511;
        __shared__ float cds[2][4];
        __shared__ float hid[2][64];
        if (t < 6) {
            int r = t / 3, d = t - 3 * r;
            cds[r][d] = coords[(size_t)row0 * 3 + t];
        }
        __syncthreads();
        {
            int r = t >> 6;          // 0 or 1
            int ch = t & 63;
            float v = fb0[ch];
            v += cds[r][0] * fw0[0 * 64 + ch];
            v += cds[r][1] * fw0[1 * 64 + ch];
            v += cds[r][2] * fw0[2 * 64 + ch];
            hid[r][ch] = fmaxf(v, 0.0f);
        }
        __syncthreads();
        // layer 2: thread t = channel, 2 rows
        float hv0 = fb1[t], hv1 = hv0;
#pragma unroll 4
        for (int k = 0; k < 64; ++k) {
            float w = fw1[k * 128 + t];
            hv0 += hid[0][k] * w;
            hv1 += hid[1][k] * w;
        }
        hv0 = fmaxf(hv0, 0.0f);
        hv1 = fmaxf(hv1, 0.0f);
        h_bf[((size_t)row0 << 7) + t] = (__bf16)hv0;
        h_bf[((size_t)(row0 + 1) << 7) + t] = (__bf16)hv1;
        // h_t: thread t holds channel t for 2 consecutive n -> one 4B store
        *(unsigned*)(h_t + (size_t)(b * 128 + t) * 512 + n0) = pk_bf16(hv1, hv0);
    } else if (blk < 2816) {
        // ---- w0t[c][k] = uw0[perm(k)][c]; coalesced read ----
        int blk2 = blk - 2048;
        int k = blk2 >> 1;
        int c = ((blk2 & 1) << 7) + t;
        int src = (k < 128) ? k : (k + 3);
        w0t[(size_t)c * 256 + k] = (__bf16)uw0[(size_t)src * 256 + c];
    } else if (blk < 3072) {
        // ---- w1t[c][k] = uw1[k][c]; coalesced read ----
        int k = blk - 2816;
        int c = t;
        w1t[(size_t)c * 256 + k] = (__bf16)uw1[(size_t)k * 128 + c];
    } else if (blk < 3104) {
        // aw1p[s*2048 + ct*512 + q*128 + m*8 + j] = aw1[(s*32+q*8+j)*64 + ct*16+m]
        int id = (blk - 3072) * 128 + t;    // 0..4095
        int j = id & 7, m = (id >> 3) & 15, q = (id >> 7) & 3;
        int ct = (id >> 9) & 3, s = (id >> 11) & 1;
        aw1p[id] = (__bf16)aw1[(s * 32 + q * 8 + j) * 64 + ct * 16 + m];
    } else if (blk < 3112) {
        int i = (blk - 3104) * 128 + t;
        if (i < out_size) out[i] = 0.0f;
    } else {
        if (t < 64) {
            int q = t >> 4, ct = (t >> 2) & 3, r = t & 3;
            int ch = ct * 16 + q * 4 + r;
            eb[t] = ab1[ch];
            ew[t] = aw2[ch];
        }
    }
}

// ---------------- adjacency MLP via bf16 MFMA, transposed epilogue ----------
// 4096 blocks x 4 waves: blk -> (b, i-group of 4, j-quarter). Wave owns one
// i-row and 8 j-tiles (128 pairs). cj software-pipelined one tile ahead
// (only 3 regs — keeps VGPR bucket, unlike R8's 16-reg prefetch).
__global__ __launch_bounds__(256) void k_adj(
    const float* __restrict__ coords,
    const float* __restrict__ aw0, const float* __restrict__ ab0,
    const __bf16* __restrict__ aw1p,
    const float* __restrict__ eb, const float* __restrict__ ew,
    const float* __restrict__ ab2,
    __bf16* __restrict__ A)
{
    const int tid = threadIdx.x;
    const int l = tid & 63;
    const int wave = tid >> 6;
    const int q = l >> 4;
    const int m = l & 15;
    const int b = blockIdx.x >> 9;
    const int jq = blockIdx.x & 3;
    const int i = (((blockIdx.x >> 2) & 127) << 2) + wave;

    const float* ci = coords + (size_t)(b * N_ + i) * 3;
    const float ci0 = ci[0], ci1 = ci[1], ci2 = ci[2];

    f32x4 o0a, o0b, o1a, o1b;
    f32x4 w3a0, w3a1, w3b0, w3b1;
    f32x4 w4a0, w4a1, w4b0, w4b1;
    f32x4 w5a0, w5a1, w5b0, w5b1;
    {
        int base = q * 8;
        f32x4 bb0 = *(const f32x4*)(ab0 + base);
        f32x4 bb1 = *(const f32x4*)(ab0 + base + 4);
        f32x4 wa0 = *(const f32x4*)(aw0 + base);
        f32x4 wa1 = *(const f32x4*)(aw0 + base + 4);
        f32x4 wb0 = *(const f32x4*)(aw0 + 64 + base);
        f32x4 wb1 = *(const f32x4*)(aw0 + 64 + base + 4);
        f32x4 wc0 = *(const f32x4*)(aw0 + 128 + base);
        f32x4 wc1 = *(const f32x4*)(aw0 + 128 + base + 4);
        o0a = bb0 + ci0 * wa0 + ci1 * wb0 + ci2 * wc0;
        o0b = bb1 + ci0 * wa1 + ci1 * wb1 + ci2 * wc1;
        w3a0 = *(const f32x4*)(aw0 + 192 + base);
        w3a1 = *(const f32x4*)(aw0 + 192 + base + 4);
        w4a0 = *(const f32x4*)(aw0 + 256 + base);
        w4a1 = *(const f32x4*)(aw0 + 256 + base + 4);
        w5a0 = *(const f32x4*)(aw0 + 320 + base);
        w5a1 = *(const f32x4*)(aw0 + 320 + base + 4);
        base = 32 + q * 8;
        bb0 = *(const f32x4*)(ab0 + base);
        bb1 = *(const f32x4*)(ab0 + base + 4);
        wa0 = *(const f32x4*)(aw0 + base);
        wa1 = *(const f32x4*)(aw0 + base + 4);
        wb0 = *(const f32x4*)(aw0 + 64 + base);
        wb1 = *(const f32x4*)(aw0 + 64 + base + 4);
        wc0 = *(const f32x4*)(aw0 + 128 + base);
        wc1 = *(const f32x4*)(aw0 + 128 + base + 4);
        o1a = bb0 + ci0 * wa0 + ci1 * wb0 + ci2 * wc0;
        o1b = bb1 + ci0 * wa1 + ci1 * wb1 + ci2 * wc1;
        w3b0 = *(const f32x4*)(aw0 + 192 + base);
        w3b1 = *(const f32x4*)(aw0 + 192 + base + 4);
        w4b0 = *(const f32x4*)(aw0 + 256 + base);
        w4b1 = *(const f32x4*)(aw0 + 256 + base + 4);
        w5b0 = *(const f32x4*)(aw0 + 320 + base);
        w5b1 = *(const f32x4*)(aw0 + 320 + base + 4);
    }

    bf16x8 bfr[2][4];
#pragma unroll
    for (int s = 0; s < 2; ++s)
#pragma unroll
        for (int ct = 0; ct < 4; ++ct)
            bfr[s][ct] = *(const bf16x8*)(aw1p + s * 2048 + ct * 512 + q * 128 + m * 8);

    f32x4 ab1q[4], ewq[4];
#pragma unroll
    for (int ct = 0; ct < 4; ++ct) {
        ab1q[ct] = *(const f32x4*)(eb + q * 16 + ct * 4);
        ewq[ct] = *(const f32x4*)(ew + q * 16 + ct * 4);
    }
    const float ab2s = ab2[0];

    __bf16* Arow = A + ((size_t)(b * N_ + i) << 9) + jq * 128;
    const float* cjbase = coords + (size_t)(b * N_ + jq * 128 + m) * 3;

    // software pipeline: cj for tile 0
    float d0 = cjbase[0], d1 = cjbase[1], d2 = cjbase[2];

#pragma unroll 1
    for (int t = 0; t < 8; ++t) {
        // prefetch next tile's cj (3 regs only; wrap at end is harmless)
        const float* cn = cjbase + (((t + 1) & 7) * 48);
        float nd0 = cn[0], nd1 = cn[1], nd2 = cn[2];

        f32x4 v0, v1, v2, v3;
#pragma unroll
        for (int j = 0; j < 4; ++j) {
            v0[j] = fmaxf(o0a[j] + d0 * w3a0[j] + d1 * w4a0[j] + d2 * w5a0[j], 0.0f);
            v1[j] = fmaxf(o0b[j] + d0 * w3a1[j] + d1 * w4a1[j] + d2 * w5a1[j], 0.0f);
            v2[j] = fmaxf(o1a[j] + d0 * w3b0[j] + d1 * w4b0[j] + d2 * w5b0[j], 0.0f);
            v3[j] = fmaxf(o1b[j] + d0 * w3b1[j] + d1 * w4b1[j] + d2 * w5b1[j], 0.0f);
        }
        u32x4 pa, pb;
        pa[0] = pk_bf16(v0[1], v0[0]); pa[1] = pk_bf16(v0[3], v0[2]);
        pa[2] = pk_bf16(v1[1], v1[0]); pa[3] = pk_bf16(v1[3], v1[2]);
        pb[0] = pk_bf16(v2[1], v2[0]); pb[1] = pk_bf16(v2[3], v2[2]);
        pb[2] = pk_bf16(v3[1], v3[0]); pb[3] = pk_bf16(v3[3], v3[2]);
        bf16x8 a0 = __builtin_bit_cast(bf16x8, pa);
        bf16x8 a1 = __builtin_bit_cast(bf16x8, pb);

        float p0, p1, p2, p3;
        {
            f32x4 c0v = ab1q[0];
            c0v = __builtin_amdgcn_mfma_f32_16x16x32_bf16(bfr[0][0], a0, c0v, 0, 0, 0);
            c0v = __builtin_amdgcn_mfma_f32_16x16x32_bf16(bfr[1][0], a1, c0v, 0, 0, 0);
            f32x4 c1v = ab1q[1];
            c1v = __builtin_amdgcn_mfma_f32_16x16x32_bf16(bfr[0][1], a0, c1v, 0, 0, 0);
            c1v = __builtin_amdgcn_mfma_f32_16x16x32_bf16(bfr[1][1], a1, c1v, 0, 0, 0);
            f32x4 c2v = ab1q[2];
            c2v = __builtin_amdgcn_mfma_f32_16x16x32_bf16(bfr[0][2], a0, c2v, 0, 0, 0);
            c2v = __builtin_amdgcn_mfma_f32_16x16x32_bf16(bfr[1][2], a1, c2v, 0, 0, 0);
            f32x4 c3v = ab1q[3];
            c3v = __builtin_amdgcn_mfma_f32_16x16x32_bf16(bfr[0][3], a0, c3v, 0, 0, 0);
            c3v = __builtin_amdgcn_mfma_f32_16x16x32_bf16(bfr[1][3], a1, c3v, 0, 0, 0);
            p0 = fmaxf(c0v[0], 0.f) * ewq[0][0] + fmaxf(c0v[1], 0.f) * ewq[0][1]
               + fmaxf(c0v[2], 0.f) * ewq[0][2] + fmaxf(c0v[3], 0.f) * ewq[0][3];
            p1 = fmaxf(c1v[0], 0.f) * ewq[1][0] + fmaxf(c1v[1], 0.f) * ewq[1][1]
               + fmaxf(c1v[2], 0.f) * ewq[1][2] + fmaxf(c1v[3], 0.f) * ewq[1][3];
            p2 = fmaxf(c2v[0], 0.f) * ewq[2][0] + fmaxf(c2v[1], 0.f) * ewq[2][1]
               + fmaxf(c2v[2], 0.f) * ewq[2][2] + fmaxf(c2v[3], 0.f) * ewq[2][3];
            p3 = fmaxf(c3v[0], 0.f) * ewq[3][0] + fmaxf(c3v[1], 0.f) * ewq[3][1]
               + fmaxf(c3v[2], 0.f) * ewq[3][2] + fmaxf(c3v[3], 0.f) * ewq[3][3];
        }
        float p = (p0 + p1) + (p2 + p3);
        p += __shfl_xor(p, 16, 64);
        p += __shfl_xor(p, 32, 64);
        if (l < 16) Arow[(t << 4) + l] = (__bf16)fmaxf(ab2s + p, 0.0f);

        d0 = nd0; d1 = nd1; d2 = nd2;
    }
}

// ---------------- fused  V = A@h (MFMA, K-split x2)  +  update MLP ----------
// 256 blocks x 1024 thr (16 waves). Unchanged from R10.
__global__ __launch_bounds__(1024) void k_aggupd(
    const __bf16* __restrict__ A, const __bf16* __restrict__ h_t,
    const __bf16* __restrict__ h_bf, const float* __restrict__ coords,
    const float* __restrict__ uw0, const float* __restrict__ ub0,
    const __bf16* __restrict__ w0t, const __bf16* __restrict__ w1t,
    const float* __restrict__ ub1,
    float* __restrict__ out)
{
    const int t = threadIdx.x;
    const int w = t >> 6;            // wave 0..15
    const int gw = w & 7;            // n-tile
    const int ks = w >> 3;           // K-half
    const int l = t & 63;
    const int q = l >> 4;
    const int m = l & 15;
    const int row0 = blockIdx.x << 4;   // 16 GLOBAL rows, same b
    const int b = row0 >> 9;

    __shared__ __align__(16) __bf16 act[16][256];  // [row][k], k=[h|V]
    __shared__ __align__(16) __bf16 u1[16][256];
    __shared__ float vp[2][16][128];
    __shared__ float cds[16][4];

    // stage h part of act: 1024 thr x 4B covers 16x128 bf16
    {
        unsigned hv = *(const unsigned*)(h_bf + ((size_t)row0 << 7) + t * 2);
        *(unsigned*)&act[(t * 2) >> 7][(t * 2) & 127] = hv;
    }
    if (t < 48) {
        int r = t / 3, d = t - 3 * r;
        cds[r][d] = coords[(size_t)row0 * 3 + t];
    }

    // ---- aggregate: V n-tile gw, K-half ks (A indexed by global row) ----
    const __bf16* Ar = A + (size_t)(row0 + m) * 512 + ks * 256 + q * 8;
    const __bf16* hp = h_t + ((size_t)b << 16) + (size_t)(gw * 16 + m) * 512
                       + ks * 256 + q * 8;
    f32x4 acc = {0.f, 0.f, 0.f, 0.f};
#pragma unroll 4
    for (int kt = 0; kt < 8; ++kt) {
        bf16x8 av = *(const bf16x8*)(Ar + kt * 32);
        bf16x8 bv = *(const bf16x8*)(hp + kt * 32);
        acc = __builtin_amdgcn_mfma_f32_16x16x32_bf16(av, bv, acc, 0, 0, 0);
    }
#pragma unroll
    for (int r = 0; r < 4; ++r)
        vp[ks][q * 4 + r][gw * 16 + m] = acc[r];
    __syncthreads();

    // combine K-halves -> act V part (1024 thr x 2 values)
#pragma unroll
    for (int it = 0; it < 2; ++it) {
        int idx = t + it * 1024;
        int row = idx >> 7, ch = idx & 127;
        act[row][128 + ch] = (__bf16)(vp[0][row][ch] + vp[1][row][ch]);
    }
    __syncthreads();

    // ---- layer 1: col c = w*16 + m (16 waves cover 256 cols) ----
    bf16x8 af[8];
#pragma unroll
    for (int ch = 0; ch < 8; ++ch)
        af[ch] = *(const bf16x8*)&act[m][q * 8 + 32 * ch];
    {
        const int c = w * 16 + m;
        const float wx = uw0[128 * 256 + c];
        const float wy = uw0[129 * 256 + c];
        const float wz = uw0[130 * 256 + c];
        const float bias = ub0[c];
        f32x4 a1c;
#pragma unroll
        for (int r = 0; r < 4; ++r)
            a1c[r] = bias + cds[q * 4 + r][0] * wx + cds[q * 4 + r][1] * wy
                          + cds[q * 4 + r][2] * wz;
        const __bf16* wp = w0t + (size_t)c * 256 + q * 8;
#pragma unroll
        for (int ch = 0; ch < 8; ++ch) {
            bf16x8 bfr = *(const bf16x8*)(wp + 32 * ch);
            a1c = __builtin_amdgcn_mfma_f32_16x16x32_bf16(af[ch], bfr, a1c, 0, 0, 0);
        }
#pragma unroll
        for (int r = 0; r < 4; ++r)
            u1[q * 4 + r][c] = (__bf16)fmaxf(a1c[r], 0.0f);
    }
    __syncthreads();

    // ---- layer 2: cols w*16 + m on waves 0..7 ----
    if (w < 8) {
        bf16x8 af2[8];
#pragma unroll
        for (int ch = 0; ch < 8; ++ch)
            af2[ch] = *(const bf16x8*)&u1[m][q * 8 + 32 * ch];
        const int c = w * 16 + m;
        float bias = ub1[c];
        f32x4 a2c = {bias, bias, bias, bias};
        const __bf16* wp = w1t + (size_t)c * 256 + q * 8;
#pragma unroll
        for (int ch = 0; ch < 8; ++ch) {
            bf16x8 bfr = *(const bf16x8*)(wp + 32 * ch);
            a2c = __builtin_amdgcn_mfma_f32_16x16x32_bf16(af2[ch], bfr, a2c, 0, 0, 0);
        }
        float mx = fmaxf(fmaxf(a2c[0], a2c[1]), fmaxf(a2c[2], a2c[3]));
        mx = fmaxf(mx, 0.0f);
        mx = fmaxf(mx, __shfl_xor(mx, 16, 64));
        mx = fmaxf(mx, __shfl_xor(mx, 32, 64));
        if (l < 16)
            atomicMax((int*)(out + ((size_t)b << 7) + c), __float_as_int(mx));
    }
}

extern "C" void kernel_launch(void* const* d_in, const int* in_sizes, int n_in,
                              void* d_out, int out_size, void* d_ws, size_t ws_size,
                              hipStream_t stream)
{
    const float* coords = (const float*)d_in[0];
    const float* fw0 = (const float*)d_in[1];
    const float* fb0 = (const float*)d_in[2];
    const float* fw1 = (const float*)d_in[3];
    const float* fb1 = (const float*)d_in[4];
    const float* aw0 = (const float*)d_in[5];
    const float* ab0 = (const float*)d_in[6];
    const float* aw1 = (const float*)d_in[7];
    const float* ab1 = (const float*)d_in[8];
    const float* aw2 = (const float*)d_in[9];
    const float* ab2 = (const float*)d_in[10];
    const float* uw0 = (const float*)d_in[11];
    const float* ub0 = (const float*)d_in[12];
    const float* uw1 = (const float*)d_in[13];
    const float* ub1 = (const float*)d_in[14];
    float* out = (float*)d_out;

    // workspace layout
    char* ws = (char*)d_ws;
    __bf16* A    = (__bf16*)(ws);                            // 4 MB
    __bf16* h_t  = (__bf16*)(ws + (4u << 20));               // 1 MB
    __bf16* h_bf = (__bf16*)(ws + (5u << 20));               // 1 MB
    __bf16* w0t  = (__bf16*)(ws + (6u << 20));               // 128 KB
    __bf16* w1t  = (__bf16*)(ws + (6u << 20) + (128u << 10));// 64 KB
    __bf16* aw1p = (__bf16*)(ws + (6u << 20) + (192u << 10));// 8 KB
    float*  eb   = (float*)(ws + (6u << 20) + (200u << 10)); // 256 B
    float*  ew   = (float*)(ws + (6u << 20) + (201u << 10)); // 256 B

    k_stage1<<<3113, 128, 0, stream>>>(coords, fw0, fb0, fw1, fb1, aw1,
                                       ab1, aw2, uw0, uw1,
                                       h_bf, h_t, w0t, w1t, aw1p, eb, ew,
                                       out, out_size);
    k_adj<<<4096, 256, 0, stream>>>(coords, aw0, ab0, aw1p, eb, ew, ab2, A);
    k_aggupd<<<256, 1024, 0, stream>>>(A, h_t, h_bf, coords, uw0, ub0,
                                       w0t, w1t, ub1, out);
}

// Round 12
// 156.666 us; speedup vs baseline: 1.0518x; 1.0518x over previous
//
#include <hip/hip_runtime.h>
#include <hip/hip_bf16.h>

#define B_ 8
#define N_ 512

typedef __attribute__((ext_vector_type(8))) __bf16 bf16x8;
typedef __attribute__((ext_vector_type(4))) float f32x4;
typedef __attribute__((ext_vector_type(4))) unsigned int u32x4;

// pack two fp32 into bf16x2 by truncation: 1 v_perm_b32
__device__ __forceinline__ unsigned pk_bf16(float hi, float lo) {
    return __builtin_amdgcn_perm(__builtin_bit_cast(unsigned, hi),
                                 __builtin_bit_cast(unsigned, lo), 0x07060302u);
}

// ---------------- mega kernel: adj (inline prep) | node MLP | prep | zero ---
// [0,2048)     adjacency MLP, R9 geometry: (b, i-group of 4, j-half)
// [2048,3072)  node MLP, 4 rows/block
// [3072,3328)  w0t transpose (1 k-row per block, coalesced reads)
// [3328,3456)  w1t transpose (2 k-rows per block)
// [3456,3460)  zero d_out
__global__ __launch_bounds__(256) void k_mega(
    const float* __restrict__ coords,
    const float* __restrict__ fw0, const float* __restrict__ fb0,
    const float* __restrict__ fw1, const float* __restrict__ fb1,
    const float* __restrict__ aw0, const float* __restrict__ ab0,
    const float* __restrict__ aw1, const float* __restrict__ ab1,
    const float* __restrict__ aw2, const float* __restrict__ ab2,
    const float* __restrict__ uw0, const float* __restrict__ uw1,
    __bf16* __restrict__ h_bf, __bf16* __restrict__ h_t,
    __bf16* __restrict__ w0t, __bf16* __restrict__ w1t,
    __bf16* __restrict__ A,
    float* __restrict__ out, int out_size)
{
    const int blk = blockIdx.x;
    const int t = threadIdx.x;

    if (blk < 2048) {
        // ================= adjacency MLP (R9 inner loop) =================
        __shared__ __align__(16) __bf16 s_aw1p[4096];
        __shared__ float s_eb[64], s_ew[64];

        // ---- inline prep: aw1 fragments + epilogue constants into LDS ----
        {
            const int base = t * 16;
            float tmp[16];
#pragma unroll
            for (int e = 0; e < 16; ++e) {
                int id = base + e;
                int j = id & 7, mm = (id >> 3) & 15, qq = (id >> 7) & 3;
                int ct = (id >> 9) & 3, s = (id >> 11) & 1;
                tmp[e] = aw1[(s * 32 + qq * 8 + j) * 64 + ct * 16 + mm];
            }
            // RNE cvt to bf16 (matches previous stage1 behavior)
            __bf16 bt[16];
#pragma unroll
            for (int e = 0; e < 16; ++e) bt[e] = (__bf16)tmp[e];
            *(bf16x8*)&s_aw1p[base] = *(bf16x8*)&bt[0];
            *(bf16x8*)&s_aw1p[base + 8] = *(bf16x8*)&bt[8];
            if (t < 64) {
                int qq = t >> 4, ct = (t >> 2) & 3, r = t & 3;
                int ch = ct * 16 + qq * 4 + r;
                s_eb[t] = ab1[ch];
                s_ew[t] = aw2[ch];
            }
        }
        __syncthreads();

        const int l = t & 63;
        const int wave = t >> 6;
        const int q = l >> 4;
        const int m = l & 15;
        const int b = blk >> 8;
        const int half = blk & 1;
        const int i = (((blk >> 1) & 127) << 2) + wave;

        const float* ci = coords + (size_t)(b * N_ + i) * 3;
        const float ci0 = ci[0], ci1 = ci[1], ci2 = ci[2];

        f32x4 o0a, o0b, o1a, o1b;
        f32x4 w3a0, w3a1, w3b0, w3b1;
        f32x4 w4a0, w4a1, w4b0, w4b1;
        f32x4 w5a0, w5a1, w5b0, w5b1;
        {
            int base = q * 8;
            f32x4 bb0 = *(const f32x4*)(ab0 + base);
            f32x4 bb1 = *(const f32x4*)(ab0 + base + 4);
            f32x4 wa0 = *(const f32x4*)(aw0 + base);
            f32x4 wa1 = *(const f32x4*)(aw0 + base + 4);
            f32x4 wb0 = *(const f32x4*)(aw0 + 64 + base);
            f32x4 wb1 = *(const f32x4*)(aw0 + 64 + base + 4);
            f32x4 wc0 = *(const f32x4*)(aw0 + 128 + base);
            f32x4 wc1 = *(const f32x4*)(aw0 + 128 + base + 4);
            o0a = bb0 + ci0 * wa0 + ci1 * wb0 + ci2 * wc0;
            o0b = bb1 + ci0 * wa1 + ci1 * wb1 + ci2 * wc1;
            w3a0 = *(const f32x4*)(aw0 + 192 + base);
            w3a1 = *(const f32x4*)(aw0 + 192 + base + 4);
            w4a0 = *(const f32x4*)(aw0 + 256 + base);
            w4a1 = *(const f32x4*)(aw0 + 256 + base + 4);
            w5a0 = *(const f32x4*)(aw0 + 320 + base);
            w5a1 = *(const f32x4*)(aw0 + 320 + base + 4);
            base = 32 + q * 8;
            bb0 = *(const f32x4*)(ab0 + base);
            bb1 = *(const f32x4*)(ab0 + base + 4);
            wa0 = *(const f32x4*)(aw0 + base);
            wa1 = *(const f32x4*)(aw0 + base + 4);
            wb0 = *(const f32x4*)(aw0 + 64 + base);
            wb1 = *(const f32x4*)(aw0 + 64 + base + 4);
            wc0 = *(const f32x4*)(aw0 + 128 + base);
            wc1 = *(const f32x4*)(aw0 + 128 + base + 4);
            o1a = bb0 + ci0 * wa0 + ci1 * wb0 + ci2 * wc0;
            o1b = bb1 + ci0 * wa1 + ci1 * wb1 + ci2 * wc1;
            w3b0 = *(const f32x4*)(aw0 + 192 + base);
            w3b1 = *(const f32x4*)(aw0 + 192 + base + 4);
            w4b0 = *(const f32x4*)(aw0 + 256 + base);
            w4b1 = *(const f32x4*)(aw0 + 256 + base + 4);
            w5b0 = *(const f32x4*)(aw0 + 320 + base);
            w5b1 = *(const f32x4*)(aw0 + 320 + base + 4);
        }

        bf16x8 bfr[2][4];
#pragma unroll
        for (int s = 0; s < 2; ++s)
#pragma unroll
            for (int ct = 0; ct < 4; ++ct)
                bfr[s][ct] = *(const bf16x8*)&s_aw1p[s * 2048 + ct * 512 + q * 128 + m * 8];

        f32x4 ab1q[4], ewq[4];
#pragma unroll
        for (int ct = 0; ct < 4; ++ct) {
            ab1q[ct] = *(const f32x4*)&s_eb[q * 16 + ct * 4];
            ewq[ct] = *(const f32x4*)&s_ew[q * 16 + ct * 4];
        }
        const float ab2s = ab2[0];

        __bf16* Arow = A + ((size_t)(b * N_ + i) << 9) + half * 256;
        const float* cjbase = coords + (size_t)(b * N_ + half * 256 + m) * 3;

#pragma unroll 1
        for (int tt = 0; tt < 16; ++tt) {
            const float* cj = cjbase + tt * 48;
            float d0 = cj[0], d1 = cj[1], d2 = cj[2];

            f32x4 v0, v1, v2, v3;
#pragma unroll
            for (int j = 0; j < 4; ++j) {
                v0[j] = fmaxf(o0a[j] + d0 * w3a0[j] + d1 * w4a0[j] + d2 * w5a0[j], 0.0f);
                v1[j] = fmaxf(o0b[j] + d0 * w3a1[j] + d1 * w4a1[j] + d2 * w5a1[j], 0.0f);
                v2[j] = fmaxf(o1a[j] + d0 * w3b0[j] + d1 * w4b0[j] + d2 * w5b0[j], 0.0f);
                v3[j] = fmaxf(o1b[j] + d0 * w3b1[j] + d1 * w4b1[j] + d2 * w5b1[j], 0.0f);
            }
            u32x4 pa, pb;
            pa[0] = pk_bf16(v0[1], v0[0]); pa[1] = pk_bf16(v0[3], v0[2]);
            pa[2] = pk_bf16(v1[1], v1[0]); pa[3] = pk_bf16(v1[3], v1[2]);
            pb[0] = pk_bf16(v2[1], v2[0]); pb[1] = pk_bf16(v2[3], v2[2]);
            pb[2] = pk_bf16(v3[1], v3[0]); pb[3] = pk_bf16(v3[3], v3[2]);
            bf16x8 a0 = __builtin_bit_cast(bf16x8, pa);
            bf16x8 a1 = __builtin_bit_cast(bf16x8, pb);

            float p0, p1, p2, p3;
            {
                f32x4 c0v = ab1q[0];
                c0v = __builtin_amdgcn_mfma_f32_16x16x32_bf16(bfr[0][0], a0, c0v, 0, 0, 0);
                c0v = __builtin_amdgcn_mfma_f32_16x16x32_bf16(bfr[1][0], a1, c0v, 0, 0, 0);
                f32x4 c1v = ab1q[1];
                c1v = __builtin_amdgcn_mfma_f32_16x16x32_bf16(bfr[0][1], a0, c1v, 0, 0, 0);
                c1v = __builtin_amdgcn_mfma_f32_16x16x32_bf16(bfr[1][1], a1, c1v, 0, 0, 0);
                f32x4 c2v = ab1q[2];
                c2v = __builtin_amdgcn_mfma_f32_16x16x32_bf16(bfr[0][2], a0, c2v, 0, 0, 0);
                c2v = __builtin_amdgcn_mfma_f32_16x16x32_bf16(bfr[1][2], a1, c2v, 0, 0, 0);
                f32x4 c3v = ab1q[3];
                c3v = __builtin_amdgcn_mfma_f32_16x16x32_bf16(bfr[0][3], a0, c3v, 0, 0, 0);
                c3v = __builtin_amdgcn_mfma_f32_16x16x32_bf16(bfr[1][3], a1, c3v, 0, 0, 0);
                p0 = fmaxf(c0v[0], 0.f) * ewq[0][0] + fmaxf(c0v[1], 0.f) * ewq[0][1]
                   + fmaxf(c0v[2], 0.f) * ewq[0][2] + fmaxf(c0v[3], 0.f) * ewq[0][3];
                p1 = fmaxf(c1v[0], 0.f) * ewq[1][0] + fmaxf(c1v[1], 0.f) * ewq[1][1]
                   + fmaxf(c1v[2], 0.f) * ewq[1][2] + fmaxf(c1v[3], 0.f) * ewq[1][3];
                p2 = fmaxf(c2v[0], 0.f) * ewq[2][0] + fmaxf(c2v[1], 0.f) * ewq[2][1]
                   + fmaxf(c2v[2], 0.f) * ewq[2][2] + fmaxf(c2v[3], 0.f) * ewq[2][3];
                p3 = fmaxf(c3v[0], 0.f) * ewq[3][0] + fmaxf(c3v[1], 0.f) * ewq[3][1]
                   + fmaxf(c3v[2], 0.f) * ewq[3][2] + fmaxf(c3v[3], 0.f) * ewq[3][3];
            }
            float p = (p0 + p1) + (p2 + p3);
            p += __shfl_xor(p, 16, 64);
            p += __shfl_xor(p, 32, 64);
            if (l < 16) Arow[(tt << 4) + l] = (__bf16)fmaxf(ab2s + p, 0.0f);
        }
    } else if (blk < 3072) {
        // ================= node MLP: 4 rows/block =================
        const int row0 = (blk - 2048) << 2;
        const int b = row0 >> 9;
        const int n0 = row0 & 511;
        __shared__ float cds4[4][4];
        __shared__ float hid4[4][64];
        if (t < 12) {
            int r = t / 3, d = t - 3 * r;
            cds4[r][d] = coords[(size_t)row0 * 3 + t];
        }
        __syncthreads();
        {
            int r = t >> 6, ch = t & 63;
            float v = fb0[ch];
            v += cds4[r][0] * fw0[0 * 64 + ch];
            v += cds4[r][1] * fw0[1 * 64 + ch];
            v += cds4[r][2] * fw0[2 * 64 + ch];
            hid4[r][ch] = fmaxf(v, 0.0f);
        }
        __syncthreads();
        {
            int ch = t & 127;
            int rp = (t >> 7) << 1;          // rows rp, rp+1
            float hv0 = fb1[ch], hv1 = hv0;
#pragma unroll 4
            for (int k = 0; k < 64; ++k) {
                float w = fw1[k * 128 + ch];
                hv0 += hid4[rp][k] * w;
                hv1 += hid4[rp + 1][k] * w;
            }
            hv0 = fmaxf(hv0, 0.0f);
            hv1 = fmaxf(hv1, 0.0f);
            h_bf[((size_t)(row0 + rp) << 7) + ch] = (__bf16)hv0;
            h_bf[((size_t)(row0 + rp + 1) << 7) + ch] = (__bf16)hv1;
            *(unsigned*)(h_t + (size_t)(b * 128 + ch) * 512 + n0 + rp) =
                pk_bf16(hv1, hv0);
        }
    } else if (blk < 3328) {
        // ---- w0t[c][k] = uw0[perm(k)][c]; coalesced read ----
        int k = blk - 3072;
        int c = t;
        int src = (k < 128) ? k : (k + 3);
        w0t[(size_t)c * 256 + k] = (__bf16)uw0[(size_t)src * 256 + c];
    } else if (blk < 3456) {
        // ---- w1t[c][k] = uw1[k][c]; coalesced read ----
        int id = (blk - 3328) * 256 + t;
        int c = id & 127, k = id >> 7;
        w1t[(size_t)c * 256 + k] = (__bf16)uw1[(size_t)k * 128 + c];
    } else {
        int i = (blk - 3456) * 256 + t;
        if (i < out_size) out[i] = 0.0f;
    }
}

// ---------------- fused  V = A@h (MFMA, K-split x2)  +  update MLP ----------
// 256 blocks x 1024 thr (16 waves). Unchanged from R10.
__global__ __launch_bounds__(1024) void k_aggupd(
    const __bf16* __restrict__ A, const __bf16* __restrict__ h_t,
    const __bf16* __restrict__ h_bf, const float* __restrict__ coords,
    const float* __restrict__ uw0, const float* __restrict__ ub0,
    const __bf16* __restrict__ w0t, const __bf16* __restrict__ w1t,
    const float* __restrict__ ub1,
    float* __restrict__ out)
{
    const int t = threadIdx.x;
    const int w = t >> 6;            // wave 0..15
    const int gw = w & 7;            // n-tile
    const int ks = w >> 3;           // K-half
    const int l = t & 63;
    const int q = l >> 4;
    const int m = l & 15;
    const int row0 = blockIdx.x << 4;   // 16 GLOBAL rows, same b
    const int b = row0 >> 9;

    __shared__ __align__(16) __bf16 act[16][256];  // [row][k], k=[h|V]
    __shared__ __align__(16) __bf16 u1[16][256];
    __shared__ float vp[2][16][128];
    __shared__ float cds[16][4];

    // stage h part of act: 1024 thr x 4B covers 16x128 bf16
    {
        unsigned hv = *(const unsigned*)(h_bf + ((size_t)row0 << 7) + t * 2);
        *(unsigned*)&act[(t * 2) >> 7][(t * 2) & 127] = hv;
    }
    if (t < 48) {
        int r = t / 3, d = t - 3 * r;
        cds[r][d] = coords[(size_t)row0 * 3 + t];
    }

    // ---- aggregate: V n-tile gw, K-half ks (A indexed by global row) ----
    const __bf16* Ar = A + (size_t)(row0 + m) * 512 + ks * 256 + q * 8;
    const __bf16* hp = h_t + ((size_t)b << 16) + (size_t)(gw * 16 + m) * 512
                       + ks * 256 + q * 8;
    f32x4 acc = {0.f, 0.f, 0.f, 0.f};
#pragma unroll 4
    for (int kt = 0; kt < 8; ++kt) {
        bf16x8 av = *(const bf16x8*)(Ar + kt * 32);
        bf16x8 bv = *(const bf16x8*)(hp + kt * 32);
        acc = __builtin_amdgcn_mfma_f32_16x16x32_bf16(av, bv, acc, 0, 0, 0);
    }
#pragma unroll
    for (int r = 0; r < 4; ++r)
        vp[ks][q * 4 + r][gw * 16 + m] = acc[r];
    __syncthreads();

    // combine K-halves -> act V part (1024 thr x 2 values)
#pragma unroll
    for (int it = 0; it < 2; ++it) {
        int idx = t + it * 1024;
        int row = idx >> 7, ch = idx & 127;
        act[row][128 + ch] = (__bf16)(vp[0][row][ch] + vp[1][row][ch]);
    }
    __syncthreads();

    // ---- layer 1: col c = w*16 + m (16 waves cover 256 cols) ----
    bf16x8 af[8];
#pragma unroll
    for (int ch = 0; ch < 8; ++ch)
        af[ch] = *(const bf16x8*)&act[m][q * 8 + 32 * ch];
    {
        const int c = w * 16 + m;
        const float wx = uw0[128 * 256 + c];
        const float wy = uw0[129 * 256 + c];
        const float wz = uw0[130 * 256 + c];
        const float bias = ub0[c];
        f32x4 a1c;
#pragma unroll
        for (int r = 0; r < 4; ++r)
            a1c[r] = bias + cds[q * 4 + r][0] * wx + cds[q * 4 + r][1] * wy
                          + cds[q * 4 + r][2] * wz;
        const __bf16* wp = w0t + (size_t)c * 256 + q * 8;
#pragma unroll
        for (int ch = 0; ch < 8; ++ch) {
            bf16x8 bfr = *(const bf16x8*)(wp + 32 * ch);
            a1c = __builtin_amdgcn_mfma_f32_16x16x32_bf16(af[ch], bfr, a1c, 0, 0, 0);
        }
#pragma unroll
        for (int r = 0; r < 4; ++r)
            u1[q * 4 + r][c] = (__bf16)fmaxf(a1c[r], 0.0f);
    }
    __syncthreads();

    // ---- layer 2: cols w*16 + m on waves 0..7 ----
    if (w < 8) {
        bf16x8 af2[8];
#pragma unroll
        for (int ch = 0; ch < 8; ++ch)
            af2[ch] = *(const bf16x8*)&u1[m][q * 8 + 32 * ch];
        const int c = w * 16 + m;
        float bias = ub1[c];
        f32x4 a2c = {bias, bias, bias, bias};
        const __bf16* wp = w1t + (size_t)c * 256 + q * 8;
#pragma unroll
        for (int ch = 0; ch < 8; ++ch) {
            bf16x8 bfr = *(const bf16x8*)(wp + 32 * ch);
            a2c = __builtin_amdgcn_mfma_f32_16x16x32_bf16(af2[ch], bfr, a2c, 0, 0, 0);
        }
        float mx = fmaxf(fmaxf(a2c[0], a2c[1]), fmaxf(a2c[2], a2c[3]));
        mx = fmaxf(mx, 0.0f);
        mx = fmaxf(mx, __shfl_xor(mx, 16, 64));
        mx = fmaxf(mx, __shfl_xor(mx, 32, 64));
        if (l < 16)
            atomicMax((int*)(out + ((size_t)b << 7) + c), __float_as_int(mx));
    }
}

extern "C" void kernel_launch(void* const* d_in, const int* in_sizes, int n_in,
                              void* d_out, int out_size, void* d_ws, size_t ws_size,
                              hipStream_t stream)
{
    const float* coords = (const float*)d_in[0];
    const float* fw0 = (const float*)d_in[1];
    const float* fb0 = (const float*)d_in[2];
    const float* fw1 = (const float*)d_in[3];
    const float* fb1 = (const float*)d_in[4];
    const float* aw0 = (const float*)d_in[5];
    const float* ab0 = (const float*)d_in[6];
    const float* aw1 = (const float*)d_in[7];
    const float* ab1 = (const float*)d_in[8];
    const float* aw2 = (const float*)d_in[9];
    const float* ab2 = (const float*)d_in[10];
    const float* uw0 = (const float*)d_in[11];
    const float* ub0 = (const float*)d_in[12];
    const float* uw1 = (const float*)d_in[13];
    const float* ub1 = (const float*)d_in[14];
    float* out = (float*)d_out;

    // workspace layout
    char* ws = (char*)d_ws;
    __bf16* A    = (__bf16*)(ws);                            // 4 MB
    __bf16* h_t  = (__bf16*)(ws + (4u << 20));               // 1 MB
    __bf16* h_bf = (__bf16*)(ws + (5u << 20));               // 1 MB
    __bf16* w0t  = (__bf16*)(ws + (6u << 20));               // 128 KB
    __bf16* w1t  = (__bf16*)(ws + (6u << 20) + (128u << 10));// 64 KB

    k_mega<<<3460, 256, 0, stream>>>(coords, fw0, fb0, fw1, fb1,
                                     aw0, ab0, aw1, ab1, aw2, ab2, uw0, uw1,
                                     h_bf, h_t, w0t, w1t, A, out, out_size);
    k_aggupd<<<256, 1024, 0, stream>>>(A, h_t, h_bf, coords, uw0, ub0,
                                       w0t, w1t, ub1, out);
}

// Round 14
// 139.997 us; speedup vs baseline: 1.1770x; 1.1191x over previous
//
#include <hip/hip_runtime.h>
#include <hip/hip_bf16.h>

#define B_ 8
#define N_ 512

typedef __attribute__((ext_vector_type(8))) __bf16 bf16x8;
typedef __attribute__((ext_vector_type(8))) _Float16 f16x8;
typedef __attribute__((ext_vector_type(2))) _Float16 h2;
typedef __attribute__((ext_vector_type(4))) float f32x4;
typedef __attribute__((ext_vector_type(4))) unsigned int u32x4;

// pack two fp32 into bf16x2 by truncation: 1 v_perm_b32
__device__ __forceinline__ unsigned pk_bf16(float hi, float lo) {
    return __builtin_amdgcn_perm(__builtin_bit_cast(unsigned, hi),
                                 __builtin_bit_cast(unsigned, lo), 0x07060302u);
}

__device__ __forceinline__ h2 h2pack(float a, float b) {
    h2 r; r[0] = (_Float16)a; r[1] = (_Float16)b; return r;
}
__device__ __forceinline__ h2 h2splat(float a) {
    _Float16 x = (_Float16)a; h2 r; r[0] = x; r[1] = x; return r;
}

// ---------------- mega kernel: adj (inline prep) | node MLP | prep | zero ---
// [0,2048)     adjacency MLP, R9 geometry, layer-0 in packed fp16
// [2048,3072)  node MLP, 4 rows/block
// [3072,3328)  w0t transpose (coalesced reads)
// [3328,3456)  w1t transpose
// [3456,3460)  zero d_out
__global__ __launch_bounds__(256) void k_mega(
    const float* __restrict__ coords,
    const float* __restrict__ fw0, const float* __restrict__ fb0,
    const float* __restrict__ fw1, const float* __restrict__ fb1,
    const float* __restrict__ aw0, const float* __restrict__ ab0,
    const float* __restrict__ aw1, const float* __restrict__ ab1,
    const float* __restrict__ aw2, const float* __restrict__ ab2,
    const float* __restrict__ uw0, const float* __restrict__ uw1,
    __bf16* __restrict__ h_bf, __bf16* __restrict__ h_t,
    __bf16* __restrict__ w0t, __bf16* __restrict__ w1t,
    __bf16* __restrict__ A,
    float* __restrict__ out, int out_size)
{
    const int blk = blockIdx.x;
    const int t = threadIdx.x;

    if (blk < 2048) {
        // ================= adjacency MLP =================
        __shared__ __align__(16) _Float16 s_aw1p[4096];
        __shared__ float s_eb[64], s_ew[64];

        // ---- inline prep: aw1 fragments (f16) + epilogue constants ----
        {
            const int base = t * 16;
            _Float16 bt[16];
#pragma unroll
            for (int e = 0; e < 16; ++e) {
                int id = base + e;
                int j = id & 7, mm = (id >> 3) & 15, qq = (id >> 7) & 3;
                int ct = (id >> 9) & 3, s = (id >> 11) & 1;
                bt[e] = (_Float16)aw1[(s * 32 + qq * 8 + j) * 64 + ct * 16 + mm];
            }
            *(f16x8*)&s_aw1p[base] = *(f16x8*)&bt[0];
            *(f16x8*)&s_aw1p[base + 8] = *(f16x8*)&bt[8];
            if (t < 64) {
                int qq = t >> 4, ct = (t >> 2) & 3, r = t & 3;
                int ch = ct * 16 + qq * 4 + r;
                s_eb[t] = ab1[ch];
                s_ew[t] = aw2[ch];
            }
        }
        __syncthreads();

        const int l = t & 63;
        const int wave = t >> 6;
        const int q = l >> 4;
        const int m = l & 15;
        const int b = blk >> 8;
        const int half = blk & 1;
        const int i = (((blk >> 1) & 127) << 2) + wave;

        const float* ci = coords + (size_t)(b * N_ + i) * 3;
        const float ci0 = ci[0], ci1 = ci[1], ci2 = ci[2];

        // layer-0 constants in packed fp16: oh (ci folded), w3/4/5 pairs.
        // index k: 0..3 -> s=0 ch q*8+{0..7}, 4..7 -> s=1 (ch+32)
        h2 oh[8], w3h[8], w4h[8], w5h[8];
        {
#pragma unroll
            for (int s = 0; s < 2; ++s) {
                int base = s * 32 + q * 8;
                f32x4 bb0 = *(const f32x4*)(ab0 + base);
                f32x4 bb1 = *(const f32x4*)(ab0 + base + 4);
                f32x4 wa0 = *(const f32x4*)(aw0 + base);
                f32x4 wa1 = *(const f32x4*)(aw0 + base + 4);
                f32x4 wb0 = *(const f32x4*)(aw0 + 64 + base);
                f32x4 wb1 = *(const f32x4*)(aw0 + 64 + base + 4);
                f32x4 wc0 = *(const f32x4*)(aw0 + 128 + base);
                f32x4 wc1 = *(const f32x4*)(aw0 + 128 + base + 4);
                f32x4 oa = bb0 + ci0 * wa0 + ci1 * wb0 + ci2 * wc0;
                f32x4 ob = bb1 + ci0 * wa1 + ci1 * wb1 + ci2 * wc1;
                f32x4 w3a = *(const f32x4*)(aw0 + 192 + base);
                f32x4 w3b = *(const f32x4*)(aw0 + 192 + base + 4);
                f32x4 w4a = *(const f32x4*)(aw0 + 256 + base);
                f32x4 w4b = *(const f32x4*)(aw0 + 256 + base + 4);
                f32x4 w5a = *(const f32x4*)(aw0 + 320 + base);
                f32x4 w5b = *(const f32x4*)(aw0 + 320 + base + 4);
                oh[s * 4 + 0] = h2pack(oa[0], oa[1]);
                oh[s * 4 + 1] = h2pack(oa[2], oa[3]);
                oh[s * 4 + 2] = h2pack(ob[0], ob[1]);
                oh[s * 4 + 3] = h2pack(ob[2], ob[3]);
                w3h[s * 4 + 0] = h2pack(w3a[0], w3a[1]);
                w3h[s * 4 + 1] = h2pack(w3a[2], w3a[3]);
                w3h[s * 4 + 2] = h2pack(w3b[0], w3b[1]);
                w3h[s * 4 + 3] = h2pack(w3b[2], w3b[3]);
                w4h[s * 4 + 0] = h2pack(w4a[0], w4a[1]);
                w4h[s * 4 + 1] = h2pack(w4a[2], w4a[3]);
                w4h[s * 4 + 2] = h2pack(w4b[0], w4b[1]);
                w4h[s * 4 + 3] = h2pack(w4b[2], w4b[3]);
                w5h[s * 4 + 0] = h2pack(w5a[0], w5a[1]);
                w5h[s * 4 + 1] = h2pack(w5a[2], w5a[3]);
                w5h[s * 4 + 2] = h2pack(w5b[0], w5b[1]);
                w5h[s * 4 + 3] = h2pack(w5b[2], w5b[3]);
            }
        }

        f16x8 bfr[2][4];
#pragma unroll
        for (int s = 0; s < 2; ++s)
#pragma unroll
            for (int ct = 0; ct < 4; ++ct)
                bfr[s][ct] = *(const f16x8*)&s_aw1p[s * 2048 + ct * 512 + q * 128 + m * 8];

        f32x4 ab1q[4], ewq[4];
#pragma unroll
        for (int ct = 0; ct < 4; ++ct) {
            ab1q[ct] = *(const f32x4*)&s_eb[q * 16 + ct * 4];
            ewq[ct] = *(const f32x4*)&s_ew[q * 16 + ct * 4];
        }
        const float ab2s = ab2[0];

        __bf16* Arow = A + ((size_t)(b * N_ + i) << 9) + half * 256;
        const float* cjbase = coords + (size_t)(b * N_ + half * 256 + m) * 3;
        const h2 zero2 = h2splat(0.0f);

#pragma unroll 1
        for (int tt = 0; tt < 16; ++tt) {
            const float* cj = cjbase + tt * 48;
            h2 d0h = h2splat(cj[0]);
            h2 d1h = h2splat(cj[1]);
            h2 d2h = h2splat(cj[2]);

            // layer 0: relu(o + cj.w) in packed fp16 — results pre-packed
            u32x4 pa, pb;
#pragma unroll
            for (int k = 0; k < 4; ++k) {
                h2 va = __builtin_elementwise_max(
                    __builtin_elementwise_fma(d0h, w3h[k],
                    __builtin_elementwise_fma(d1h, w4h[k],
                    __builtin_elementwise_fma(d2h, w5h[k], oh[k]))), zero2);
                h2 vb = __builtin_elementwise_max(
                    __builtin_elementwise_fma(d0h, w3h[4 + k],
                    __builtin_elementwise_fma(d1h, w4h[4 + k],
                    __builtin_elementwise_fma(d2h, w5h[4 + k], oh[4 + k]))), zero2);
                pa[k] = __builtin_bit_cast(unsigned, va);
                pb[k] = __builtin_bit_cast(unsigned, vb);
            }
            f16x8 a0 = __builtin_bit_cast(f16x8, pa);
            f16x8 a1 = __builtin_bit_cast(f16x8, pb);

            // layer 1 transposed MFMA (f16); ab1 folded into C-init
            float p0, p1, p2, p3;
            {
                f32x4 c0v = ab1q[0];
                c0v = __builtin_amdgcn_mfma_f32_16x16x32_f16(bfr[0][0], a0, c0v, 0, 0, 0);
                c0v = __builtin_amdgcn_mfma_f32_16x16x32_f16(bfr[1][0], a1, c0v, 0, 0, 0);
                f32x4 c1v = ab1q[1];
                c1v = __builtin_amdgcn_mfma_f32_16x16x32_f16(bfr[0][1], a0, c1v, 0, 0, 0);
                c1v = __builtin_amdgcn_mfma_f32_16x16x32_f16(bfr[1][1], a1, c1v, 0, 0, 0);
                f32x4 c2v = ab1q[2];
                c2v = __builtin_amdgcn_mfma_f32_16x16x32_f16(bfr[0][2], a0, c2v, 0, 0, 0);
                c2v = __builtin_amdgcn_mfma_f32_16x16x32_f16(bfr[1][2], a1, c2v, 0, 0, 0);
                f32x4 c3v = ab1q[3];
                c3v = __builtin_amdgcn_mfma_f32_16x16x32_f16(bfr[0][3], a0, c3v, 0, 0, 0);
                c3v = __builtin_amdgcn_mfma_f32_16x16x32_f16(bfr[1][3], a1, c3v, 0, 0, 0);
                p0 = fmaxf(c0v[0], 0.f) * ewq[0][0] + fmaxf(c0v[1], 0.f) * ewq[0][1]
                   + fmaxf(c0v[2], 0.f) * ewq[0][2] + fmaxf(c0v[3], 0.f) * ewq[0][3];
                p1 = fmaxf(c1v[0], 0.f) * ewq[1][0] + fmaxf(c1v[1], 0.f) * ewq[1][1]
                   + fmaxf(c1v[2], 0.f) * ewq[1][2] + fmaxf(c1v[3], 0.f) * ewq[1][3];
                p2 = fmaxf(c2v[0], 0.f) * ewq[2][0] + fmaxf(c2v[1], 0.f) * ewq[2][1]
                   + fmaxf(c2v[2], 0.f) * ewq[2][2] + fmaxf(c2v[3], 0.f) * ewq[2][3];
                p3 = fmaxf(c3v[0], 0.f) * ewq[3][0] + fmaxf(c3v[1], 0.f) * ewq[3][1]
                   + fmaxf(c3v[2], 0.f) * ewq[3][2] + fmaxf(c3v[3], 0.f) * ewq[3][3];
            }
            float p = (p0 + p1) + (p2 + p3);
            p += __shfl_xor(p, 16, 64);
            p += __shfl_xor(p, 32, 64);
            if (l < 16) Arow[(tt << 4) + l] = (__bf16)fmaxf(ab2s + p, 0.0f);
        }
    } else if (blk < 3072) {
        // ================= node MLP: 4 rows/block =================
        const int row0 = (blk - 2048) << 2;
        const int b = row0 >> 9;
        const int n0 = row0 & 511;
        __shared__ float cds4[4][4];
        __shared__ float hid4[4][64];
        if (t < 12) {
            int r = t / 3, d = t - 3 * r;
            cds4[r][d] = coords[(size_t)row0 * 3 + t];
        }
        __syncthreads();
        {
            int r = t >> 6, ch = t & 63;
            float v = fb0[ch];
            v += cds4[r][0] * fw0[0 * 64 + ch];
            v += cds4[r][1] * fw0[1 * 64 + ch];
            v += cds4[r][2] * fw0[2 * 64 + ch];
            hid4[r][ch] = fmaxf(v, 0.0f);
        }
        __syncthreads();
        {
            int ch = t & 127;
            int rp = (t >> 7) << 1;          // rows rp, rp+1
            float hv0 = fb1[ch], hv1 = hv0;
#pragma unroll 4
            for (int k = 0; k < 64; ++k) {
                float w = fw1[k * 128 + ch];
                hv0 += hid4[rp][k] * w;
                hv1 += hid4[rp + 1][k] * w;
            }
            hv0 = fmaxf(hv0, 0.0f);
            hv1 = fmaxf(hv1, 0.0f);
            h_bf[((size_t)(row0 + rp) << 7) + ch] = (__bf16)hv0;
            h_bf[((size_t)(row0 + rp + 1) << 7) + ch] = (__bf16)hv1;
            *(unsigned*)(h_t + (size_t)(b * 128 + ch) * 512 + n0 + rp) =
                pk_bf16(hv1, hv0);
        }
    } else if (blk < 3328) {
        // ---- w0t[c][k] = uw0[perm(k)][c]; coalesced read ----
        int k = blk - 3072;
        int c = t;
        int src = (k < 128) ? k : (k + 3);
        w0t[(size_t)c * 256 + k] = (__bf16)uw0[(size_t)src * 256 + c];
    } else if (blk < 3456) {
        // ---- w1t[c][k] = uw1[k][c]; coalesced read ----
        int id = (blk - 3328) * 256 + t;
        int c = id & 127, k = id >> 7;
        w1t[(size_t)c * 256 + k] = (__bf16)uw1[(size_t)k * 128 + c];
    } else {
        int i = (blk - 3456) * 256 + t;
        if (i < out_size) out[i] = 0.0f;
    }
}

// ---------------- fused  V = A@h (MFMA, K-split x2)  +  update MLP ----------
// 256 blocks x 1024 thr (16 waves). act/u1 rows padded 256->264 bf16 to break
// the 512B-stride 16-way LDS bank conflict on A-fragment ds_read_b128.
__global__ __launch_bounds__(1024) void k_aggupd(
    const __bf16* __restrict__ A, const __bf16* __restrict__ h_t,
    const __bf16* __restrict__ h_bf, const float* __restrict__ coords,
    const float* __restrict__ uw0, const float* __restrict__ ub0,
    const __bf16* __restrict__ w0t, const __bf16* __restrict__ w1t,
    const float* __restrict__ ub1,
    float* __restrict__ out)
{
    const int t = threadIdx.x;
    const int w = t >> 6;            // wave 0..15
    const int gw = w & 7;            // n-tile
    const int ks = w >> 3;           // K-half
    const int l = t & 63;
    const int q = l >> 4;
    const int m = l & 15;
    const int row0 = blockIdx.x << 4;   // 16 GLOBAL rows, same b
    const int b = row0 >> 9;

    __shared__ __align__(16) __bf16 act[16][264];  // [row][k], k=[h|V], padded
    __shared__ __align__(16) __bf16 u1[16][264];
    __shared__ float vp[2][16][128];
    __shared__ float cds[16][4];

    // stage h part of act: 1024 thr x 4B covers 16x128 bf16
    {
        unsigned hv = *(const unsigned*)(h_bf + ((size_t)row0 << 7) + t * 2);
        *(unsigned*)&act[(t * 2) >> 7][(t * 2) & 127] = hv;
    }
    if (t < 48) {
        int r = t / 3, d = t - 3 * r;
        cds[r][d] = coords[(size_t)row0 * 3 + t];
    }

    // ---- aggregate: V n-tile gw, K-half ks (A indexed by global row) ----
    const __bf16* Ar = A + (size_t)(row0 + m) * 512 + ks * 256 + q * 8;
    const __bf16* hp = h_t + ((size_t)b << 16) + (size_t)(gw * 16 + m) * 512
                       + ks * 256 + q * 8;
    f32x4 acc = {0.f, 0.f, 0.f, 0.f};
#pragma unroll 4
    for (int kt = 0; kt < 8; ++kt) {
        bf16x8 av = *(const bf16x8*)(Ar + kt * 32);
        bf16x8 bv = *(const bf16x8*)(hp + kt * 32);
        acc = __builtin_amdgcn_mfma_f32_16x16x32_bf16(av, bv, acc, 0, 0, 0);
    }
#pragma unroll
    for (int r = 0; r < 4; ++r)
        vp[ks][q * 4 + r][gw * 16 + m] = acc[r];
    __syncthreads();

    // combine K-halves -> act V part (1024 thr x 2 values)
#pragma unroll
    for (int it = 0; it < 2; ++it) {
        int idx = t + it * 1024;
        int row = idx >> 7, ch = idx & 127;
        act[row][128 + ch] = (__bf16)(vp[0][row][ch] + vp[1][row][ch]);
    }
    __syncthreads();

    // ---- layer 1: col c = w*16 + m (16 waves cover 256 cols) ----
    bf16x8 af[8];
#pragma unroll
    for (int ch = 0; ch < 8; ++ch)
        af[ch] = *(const bf16x8*)&act[m][q * 8 + 32 * ch];
    {
        const int c = w * 16 + m;
        const float wx = uw0[128 * 256 + c];
        const float wy = uw0[129 * 256 + c];
        const float wz = uw0[130 * 256 + c];
        const float bias = ub0[c];
        f32x4 a1c;
#pragma unroll
        for (int r = 0; r < 4; ++r)
            a1c[r] = bias + cds[q * 4 + r][0] * wx + cds[q * 4 + r][1] * wy
                          + cds[q * 4 + r][2] * wz;
        const __bf16* wp = w0t + (size_t)c * 256 + q * 8;
#pragma unroll
        for (int ch = 0; ch < 8; ++ch) {
            bf16x8 bfr = *(const bf16x8*)(wp + 32 * ch);
            a1c = __builtin_amdgcn_mfma_f32_16x16x32_bf16(af[ch], bfr, a1c, 0, 0, 0);
        }
#pragma unroll
        for (int r = 0; r < 4; ++r)
            u1[q * 4 + r][c] = (__bf16)fmaxf(a1c[r], 0.0f);
    }
    __syncthreads();

    // ---- layer 2: cols w*16 + m on waves 0..7 ----
    if (w < 8) {
        bf16x8 af2[8];
#pragma unroll
        for (int ch = 0; ch < 8; ++ch)
            af2[ch] = *(const bf16x8*)&u1[m][q * 8 + 32 * ch];
        const int c = w * 16 + m;
        float bias = ub1[c];
        f32x4 a2c = {bias, bias, bias, bias};
        const __bf16* wp = w1t + (size_t)c * 256 + q * 8;
#pragma unroll
        for (int ch = 0; ch < 8; ++ch) {
            bf16x8 bfr = *(const bf16x8*)(wp + 32 * ch);
            a2c = __builtin_amdgcn_mfma_f32_16x16x32_bf16(af2[ch], bfr, a2c, 0, 0, 0);
        }
        float mx = fmaxf(fmaxf(a2c[0], a2c[1]), fmaxf(a2c[2], a2c[3]));
        mx = fmaxf(mx, 0.0f);
        mx = fmaxf(mx, __shfl_xor(mx, 16, 64));
        mx = fmaxf(mx, __shfl_xor(mx, 32, 64));
        if (l < 16)
            atomicMax((int*)(out + ((size_t)b << 7) + c), __float_as_int(mx));
    }
}

extern "C" void kernel_launch(void* const* d_in, const int* in_sizes, int n_in,
                              void* d_out, int out_size, void* d_ws, size_t ws_size,
                              hipStream_t stream)
{
    const float* coords = (const float*)d_in[0];
    const float* fw0 = (const float*)d_in[1];
    const float* fb0 = (const float*)d_in[2];
    const float* fw1 = (const float*)d_in[3];
    const float* fb1 = (const float*)d_in[4];
    const float* aw0 = (const float*)d_in[5];
    const float* ab0 = (const float*)d_in[6];
    const float* aw1 = (const float*)d_in[7];
    const float* ab1 = (const float*)d_in[8];
    const float* aw2 = (const float*)d_in[9];
    const float* ab2 = (const float*)d_in[10];
    const float* uw0 = (const float*)d_in[11];
    const float* ub0 = (const float*)d_in[12];
    const float* uw1 = (const float*)d_in[13];
    const float* ub1 = (const float*)d_in[14];
    float* out = (float*)d_out;

    // workspace layout
    char* ws = (char*)d_ws;
    __bf16* A    = (__bf16*)(ws);                            // 4 MB
    __bf16* h_t  = (__bf16*)(ws + (4u << 20));               // 1 MB
    __bf16* h_bf = (__bf16*)(ws + (5u << 20));               // 1 MB
    __bf16* w0t  = (__bf16*)(ws + (6u << 20));               // 128 KB
    __bf16* w1t  = (__bf16*)(ws + (6u << 20) + (128u << 10));// 64 KB

    k_mega<<<3460, 256, 0, stream>>>(coords, fw0, fb0, fw1, fb1,
                                     aw0, ab0, aw1, ab1, aw2, ab2, uw0, uw1,
                                     h_bf, h_t, w0t, w1t, A, out, out_size);
    k_aggupd<<<256, 1024, 0, stream>>>(A, h_t, h_bf, coords, uw0, ub0,
                                       w0t, w1t, ub1, out);
}